// Round 1
// baseline (10183.662 us; speedup 1.0000x reference)
//
#include <hip/hip_runtime.h>

// Softmax splatting (softsplat 'soft' mode) with metric == 1.
// B=8, C=128, H=256, W=256, f32 in/out.
// out = [warped (B,C,H,W) | metric (B,1,H,W)=1.0]

static constexpr int B = 8, C = 128, H = 256, W = 256;
static constexpr int HW = H * W;
static constexpr float E1  = 2.7182818284590452354f;  // exp(1)
static constexpr float EPS = 1e-7f;
static constexpr int CG  = 8;        // channel groups per pixel
static constexpr int CPG = C / CG;   // 16 channels per group

__global__ __launch_bounds__(256) void splat_kernel(
    const float* __restrict__ feat, const float* __restrict__ flow,
    float* __restrict__ num, float* __restrict__ den)
{
    const int x  = threadIdx.x;          // 0..255  (= W)
    const int by = blockIdx.x;           // b*H + y
    const int b  = by >> 8;
    const int y  = by & (H - 1);
    const int cg = blockIdx.y;           // 0..CG-1

    const float fx = (float)x + flow[(b * 2 * H + y) * W + x];
    const float fy = (float)y + flow[((b * 2 + 1) * H + y) * W + x];
    const float x0f = floorf(fx), y0f = floorf(fy);
    const int ix0 = (int)x0f, iy0 = (int)y0f;
    const float ax = fx - x0f, ay = fy - y0f;
    const float w00 = (1.f - ax) * (1.f - ay);
    const float w10 = ax * (1.f - ay);
    const float w01 = (1.f - ax) * ay;
    const float w11 = ax * ay;
    const bool vx0 = (unsigned)ix0       < (unsigned)W;
    const bool vx1 = (unsigned)(ix0 + 1) < (unsigned)W;
    const bool vy0 = (unsigned)iy0       < (unsigned)H;
    const bool vy1 = (unsigned)(iy0 + 1) < (unsigned)H;
    const bool v00 = vx0 && vy0, v10 = vx1 && vy0;
    const bool v01 = vx0 && vy1, v11 = vx1 && vy1;
    const int t00 = iy0 * W + ix0;       // target offset within one (H,W) plane
    const int t01 = t00 + W;

    if (cg == 0) {
        float* dn = den + b * HW;
        if (v00) atomicAdd(dn + t00,     w00);
        if (v10) atomicAdd(dn + t00 + 1, w10);
        if (v01) atomicAdd(dn + t01,     w01);
        if (v11) atomicAdd(dn + t01 + 1, w11);
    }

    const int c0 = cg * CPG;
    const float* fp = feat + ((size_t)(b * C + c0)) * HW + y * W + x;
    float*       np = num  + ((size_t)(b * C + c0)) * HW;
    #pragma unroll 4
    for (int c = 0; c < CPG; ++c) {
        const float v = fp[(size_t)c * HW];
        float* nc = np + (size_t)c * HW;
        if (v00) atomicAdd(nc + t00,     v * w00);
        if (v10) atomicAdd(nc + t00 + 1, v * w10);
        if (v01) atomicAdd(nc + t01,     v * w01);
        if (v11) atomicAdd(nc + t01 + 1, v * w11);
    }
}

__global__ __launch_bounds__(256) void normalize_kernel(
    float* __restrict__ num, float* __restrict__ den)
{
    const int x   = threadIdx.x;
    const int by  = blockIdx.x;          // b*H + y
    const int b   = by >> 8;
    const int pix = by * W + x;          // = b*HW + y*W + x
    const float d = den[pix];
    const float s = E1 / (E1 * d + EPS);
    float* p = num + (size_t)b * (C - 1) * HW + pix;  // = num + (b*C)*HW + (y*W+x)
    #pragma unroll 8
    for (int c = 0; c < C; ++c) p[(size_t)c * HW] *= s;
    den[pix] = 1.0f;                     // metric output
}

extern "C" void kernel_launch(void* const* d_in, const int* in_sizes, int n_in,
                              void* d_out, int out_size, void* d_ws, size_t ws_size,
                              hipStream_t stream) {
    const float* feat = (const float*)d_in[0];
    const float* flow = (const float*)d_in[1];
    float* out = (float*)d_out;
    float* num = out;                         // (B,C,H,W)
    float* den = out + (size_t)B * C * HW;    // (B,1,H,W) — scratch, then metric=1

    hipMemsetAsync(d_out, 0, (size_t)out_size * sizeof(float), stream);
    splat_kernel<<<dim3(B * H, CG), 256, 0, stream>>>(feat, flow, num, den);
    normalize_kernel<<<B * H, 256, 0, stream>>>(num, den);
}

// Round 2
// 2005.854 us; speedup vs baseline: 5.0770x; 5.0770x over previous
//
#include <hip/hip_runtime.h>

// Softmax splatting (softsplat 'soft', metric==1) via destination-binned GATHER.
// B=8, C=128, H=256, W=256, f32. out = [warped (B,C,H,W) | metric (B,1,H,W)=1]
//
// Pipeline: count -> scan(3 kernels) -> fill sorted source lists -> gather
// (writes final normalized output; no atomics on the fat channel data).

typedef unsigned int u32;

static constexpr int B = 8, C = 128, H = 256, W = 256;
static constexpr int HW = H * W;
static constexpr int PH = H + 1, PW = W + 1;         // padded floor-cell grid (ix0,iy0 in [-1,255])
static constexpr int NC = B * PH * PW;               // 528392 cells
static constexpr int S  = B * HW;                    // 524288 sources
static constexpr float E1  = 2.7182818284590452354f; // exp(1) (metric == 1)
static constexpr float EPS = 1e-7f;
static constexpr int CHUNK = 1024;                   // scan elements per block
static constexpr int NBLK  = (NC + CHUNK - 1) / CHUNK;  // 517

// ---------------- binning ----------------

__global__ __launch_bounds__(256) void count_kernel(const float* __restrict__ flow,
                                                    u32* __restrict__ counts)
{
    const int x = threadIdx.x, by = blockIdx.x, b = by >> 8, y = by & 255;
    const float fx = (float)x + flow[(b * 2) * HW + y * W + x];
    const float fy = (float)y + flow[(b * 2 + 1) * HW + y * W + x];
    const int ix0 = (int)floorf(fx), iy0 = (int)floorf(fy);
    if (ix0 >= -1 && ix0 < W && iy0 >= -1 && iy0 < H)
        atomicAdd(&counts[(b * PH + iy0 + 1) * PW + (ix0 + 1)], 1u);
}

__global__ __launch_bounds__(256) void scan_blocks(const u32* __restrict__ in,
                                                   u32* __restrict__ out,
                                                   u32* __restrict__ bsum)
{
    __shared__ u32 sd[256];
    const int tid = threadIdx.x;
    const int base = blockIdx.x * CHUNK + tid * 4;
    u32 v0 = 0, v1 = 0, v2 = 0, v3 = 0;
    if (base + 3 < NC) {
        const uint4 q = *(const uint4*)(in + base);
        v0 = q.x; v1 = q.y; v2 = q.z; v3 = q.w;
    } else {
        if (base     < NC) v0 = in[base];
        if (base + 1 < NC) v1 = in[base + 1];
        if (base + 2 < NC) v2 = in[base + 2];
    }
    const u32 t = v0 + v1 + v2 + v3;
    sd[tid] = t; __syncthreads();
    for (int o = 1; o < 256; o <<= 1) {
        const u32 a = (tid >= o) ? sd[tid - o] : 0u;
        __syncthreads();
        sd[tid] += a;
        __syncthreads();
    }
    const u32 excl = sd[tid] - t;
    if (base + 3 < NC) {
        uint4 q; q.x = excl; q.y = excl + v0; q.z = excl + v0 + v1; q.w = excl + v0 + v1 + v2;
        *(uint4*)(out + base) = q;
    } else {
        if (base     < NC) out[base]     = excl;
        if (base + 1 < NC) out[base + 1] = excl + v0;
        if (base + 2 < NC) out[base + 2] = excl + v0 + v1;
    }
    if (tid == 255) bsum[blockIdx.x] = sd[255];
}

__global__ __launch_bounds__(1024) void scan_bsum(u32* __restrict__ bsum,
                                                  u32* __restrict__ off)
{
    __shared__ u32 sd[1024];
    const int tid = threadIdx.x;
    const u32 v = (tid < NBLK) ? bsum[tid] : 0u;
    sd[tid] = v; __syncthreads();
    for (int o = 1; o < 1024; o <<= 1) {
        const u32 a = (tid >= o) ? sd[tid - o] : 0u;
        __syncthreads();
        sd[tid] += a;
        __syncthreads();
    }
    if (tid < NBLK) bsum[tid] = sd[tid] - v;
    if (tid == 1023) off[NC] = sd[1023];   // grand total
}

__global__ __launch_bounds__(256) void scan_add(u32* __restrict__ off,
                                                const u32* __restrict__ bsum)
{
    const u32 add = bsum[blockIdx.x];
    if (add == 0) return;                  // uniform per block
    const int base = blockIdx.x * CHUNK + threadIdx.x * 4;
    if (base + 3 < NC) {
        uint4 q = *(uint4*)(off + base);
        q.x += add; q.y += add; q.z += add; q.w += add;
        *(uint4*)(off + base) = q;
    } else {
        for (int k = 0; k < 4; ++k)
            if (base + k < NC) off[base + k] += add;
    }
}

__global__ __launch_bounds__(256) void fill_kernel(const float* __restrict__ flow,
                                                   const u32* __restrict__ off,
                                                   u32* __restrict__ cur,
                                                   u32* __restrict__ lpos,
                                                   float* __restrict__ lfx,
                                                   float* __restrict__ lfy)
{
    const int x = threadIdx.x, by = blockIdx.x, b = by >> 8, y = by & 255;
    const float fx = (float)x + flow[(b * 2) * HW + y * W + x];
    const float fy = (float)y + flow[(b * 2 + 1) * HW + y * W + x];
    const int ix0 = (int)floorf(fx), iy0 = (int)floorf(fy);
    if (ix0 >= -1 && ix0 < W && iy0 >= -1 && iy0 < H) {
        const int cell = (b * PH + iy0 + 1) * PW + (ix0 + 1);
        const u32 slot = off[cell] + atomicAdd(&cur[cell], 1u);
        lpos[slot] = (u32)(y * W + x);
        lfx[slot]  = fx;
        lfy[slot]  = fy;
    }
}

// ---------------- gather ----------------
// Output (oy,ox) gathers sources with floor-cell in {oy-1,oy} x {ox-1,ox}.
// Cells (r,ox) and (r,ox+1) are adjacent in the flat offsets array, so each
// row r contributes ONE contiguous list range [off[r,ox], off[r,ox+2]).
// Weight: w = (1-|fx-ox|)*(1-|fy-oy|)  (== reference bilinear corner weight).

__global__ __launch_bounds__(256) void gather_kernel(
    const float* __restrict__ feat, const u32* __restrict__ off,
    const u32* __restrict__ lpos, const float* __restrict__ lfx,
    const float* __restrict__ lfy, float* __restrict__ out)
{
    const int t = threadIdx.x;
    const int tile = blockIdx.x, b = blockIdx.y;
    const int ox = ((tile & 15) << 4) | (t & 15);
    const int oy = ((tile >> 4) << 4) | (t >> 4);
    const int opix = oy * W + ox;
    const u32 rb0 = (u32)((b * PH + oy) * PW + ox);
    const u32 s0 = off[rb0],      e0 = off[rb0 + 2];
    const u32 s1 = off[rb0 + PW], e1 = off[rb0 + PW + 2];
    const float fox = (float)ox, foy = (float)oy;

    // pass 1: denominator
    float den = 0.f;
    for (int rr = 0; rr < 2; ++rr) {
        u32 i = rr ? s1 : s0;
        const u32 e = rr ? e1 : e0;
        for (; i < e; ++i)
            den += (1.f - fabsf(lfx[i] - fox)) * (1.f - fabsf(lfy[i] - foy));
    }
    const float scale = E1 / (E1 * den + EPS);

    // pass 2: channels, 16 at a time (entry metadata re-reads hit L1)
    for (int ch = 0; ch < C; ch += 16) {
        float acc[16];
        #pragma unroll
        for (int c = 0; c < 16; ++c) acc[c] = 0.f;
        const float* fb = feat + (size_t)(b * C + ch) * HW;
        for (int rr = 0; rr < 2; ++rr) {
            u32 i = rr ? s1 : s0;
            const u32 e = rr ? e1 : e0;
            for (; i < e; ++i) {
                const float w = (1.f - fabsf(lfx[i] - fox)) * (1.f - fabsf(lfy[i] - foy));
                const float* fp = fb + lpos[i];
                #pragma unroll
                for (int c = 0; c < 16; ++c)
                    acc[c] = fmaf(w, fp[(size_t)c * HW], acc[c]);
            }
        }
        float* op = out + (size_t)(b * C + ch) * HW + opix;
        #pragma unroll
        for (int c = 0; c < 16; ++c) op[(size_t)c * HW] = acc[c] * scale;
    }
    out[(size_t)(B * C) * HW + (size_t)b * HW + opix] = 1.0f;  // metric plane
}

// ---------------- fallback (round-1 atomic path) ----------------

static constexpr int CG = 8, CPG = C / CG;

__global__ __launch_bounds__(256) void splat_kernel(
    const float* __restrict__ feat, const float* __restrict__ flow,
    float* __restrict__ num, float* __restrict__ den)
{
    const int x = threadIdx.x, by = blockIdx.x, b = by >> 8, y = by & (H - 1);
    const int cg = blockIdx.y;
    const float fx = (float)x + flow[(b * 2 * H + y) * W + x];
    const float fy = (float)y + flow[((b * 2 + 1) * H + y) * W + x];
    const float x0f = floorf(fx), y0f = floorf(fy);
    const int ix0 = (int)x0f, iy0 = (int)y0f;
    const float ax = fx - x0f, ay = fy - y0f;
    const float w00 = (1.f - ax) * (1.f - ay), w10 = ax * (1.f - ay);
    const float w01 = (1.f - ax) * ay,         w11 = ax * ay;
    const bool vx0 = (unsigned)ix0       < (unsigned)W;
    const bool vx1 = (unsigned)(ix0 + 1) < (unsigned)W;
    const bool vy0 = (unsigned)iy0       < (unsigned)H;
    const bool vy1 = (unsigned)(iy0 + 1) < (unsigned)H;
    const bool v00 = vx0 && vy0, v10 = vx1 && vy0;
    const bool v01 = vx0 && vy1, v11 = vx1 && vy1;
    const int t00 = iy0 * W + ix0, t01 = t00 + W;
    if (cg == 0) {
        float* dn = den + b * HW;
        if (v00) atomicAdd(dn + t00,     w00);
        if (v10) atomicAdd(dn + t00 + 1, w10);
        if (v01) atomicAdd(dn + t01,     w01);
        if (v11) atomicAdd(dn + t01 + 1, w11);
    }
    const int c0 = cg * CPG;
    const float* fp = feat + ((size_t)(b * C + c0)) * HW + y * W + x;
    float*       np = num  + ((size_t)(b * C + c0)) * HW;
    for (int c = 0; c < CPG; ++c) {
        const float v = fp[(size_t)c * HW];
        float* nc = np + (size_t)c * HW;
        if (v00) atomicAdd(nc + t00,     v * w00);
        if (v10) atomicAdd(nc + t00 + 1, v * w10);
        if (v01) atomicAdd(nc + t01,     v * w01);
        if (v11) atomicAdd(nc + t01 + 1, v * w11);
    }
}

__global__ __launch_bounds__(256) void normalize_kernel(float* __restrict__ num,
                                                        float* __restrict__ den)
{
    const int x = threadIdx.x, by = blockIdx.x, b = by >> 8;
    const int pix = by * W + x;
    const float d = den[pix];
    const float s = E1 / (E1 * d + EPS);
    float* p = num + (size_t)b * (C - 1) * HW + pix;
    for (int c = 0; c < C; ++c) p[(size_t)c * HW] *= s;
    den[pix] = 1.0f;
}

// ---------------- launch ----------------

extern "C" void kernel_launch(void* const* d_in, const int* in_sizes, int n_in,
                              void* d_out, int out_size, void* d_ws, size_t ws_size,
                              hipStream_t stream) {
    const float* feat = (const float*)d_in[0];
    const float* flow = (const float*)d_in[1];
    float* out = (float*)d_out;

    const size_t o_counts = 0;
    const size_t o_off    = o_counts + (size_t)NC * 4;
    const size_t o_bsum   = (o_off + (size_t)(NC + 1) * 4 + 15) & ~(size_t)15;
    const size_t o_lpos   = (o_bsum + 4096 + 15) & ~(size_t)15;  // NBLK*4 = 2068 <= 4096
    const size_t o_lfx    = o_lpos + (size_t)S * 4;
    const size_t o_lfy    = o_lfx + (size_t)S * 4;
    const size_t req      = o_lfy + (size_t)S * 4;               // ~10.5 MB

    if (ws_size >= req) {
        u32*   counts = (u32*)  ((char*)d_ws + o_counts);
        u32*   off    = (u32*)  ((char*)d_ws + o_off);
        u32*   bsum   = (u32*)  ((char*)d_ws + o_bsum);
        u32*   lpos   = (u32*)  ((char*)d_ws + o_lpos);
        float* lfx    = (float*)((char*)d_ws + o_lfx);
        float* lfy    = (float*)((char*)d_ws + o_lfy);

        hipMemsetAsync(counts, 0, (size_t)NC * 4, stream);
        count_kernel<<<B * H, 256, 0, stream>>>(flow, counts);
        scan_blocks<<<NBLK, 256, 0, stream>>>(counts, off, bsum);
        scan_bsum<<<1, 1024, 0, stream>>>(bsum, off);
        scan_add<<<NBLK, 256, 0, stream>>>(off, bsum);
        hipMemsetAsync(counts, 0, (size_t)NC * 4, stream);  // reuse as cursor
        fill_kernel<<<B * H, 256, 0, stream>>>(flow, off, counts, lpos, lfx, lfy);
        gather_kernel<<<dim3(256, B), 256, 0, stream>>>(feat, off, lpos, lfx, lfy, out);
    } else {
        float* num = out;
        float* den = out + (size_t)B * C * HW;
        hipMemsetAsync(d_out, 0, (size_t)out_size * sizeof(float), stream);
        splat_kernel<<<dim3(B * H, CG), 256, 0, stream>>>(feat, flow, num, den);
        normalize_kernel<<<B * H, 256, 0, stream>>>(num, den);
    }
}

// Round 3
// 511.488 us; speedup vs baseline: 19.9099x; 3.9216x over previous
//
#include <hip/hip_runtime.h>

// Softmax splatting (softsplat 'soft', metric==1) via destination-binned GATHER
// with a feat PACK stage (planar -> per-entry contiguous) to kill line overfetch.
// B=8, C=128, H=256, W=256, f32. out = [warped (B,C,H,W) | metric (B,1,H,W)=1]

typedef unsigned int u32;

static constexpr int B = 8, C = 128, H = 256, W = 256;
static constexpr int HW = H * W;
static constexpr int PH = H + 1, PW = W + 1;         // padded floor-cell grid
static constexpr int NC = B * PH * PW;               // 528392 cells
static constexpr int S  = B * HW;                    // 524288 sources
static constexpr float E1  = 2.7182818284590452354f; // exp(1) (metric == 1)
static constexpr float EPS = 1e-7f;
static constexpr int CHUNK = 1024;
static constexpr int NBLK  = (NC + CHUNK - 1) / CHUNK;  // 517

// ---------------- binning ----------------

__global__ __launch_bounds__(256) void count_kernel(const float* __restrict__ flow,
                                                    u32* __restrict__ counts)
{
    const int x = threadIdx.x, by = blockIdx.x, b = by >> 8, y = by & 255;
    const float fx = (float)x + flow[(b * 2) * HW + y * W + x];
    const float fy = (float)y + flow[(b * 2 + 1) * HW + y * W + x];
    const int ix0 = (int)floorf(fx), iy0 = (int)floorf(fy);
    if (ix0 >= -1 && ix0 < W && iy0 >= -1 && iy0 < H)
        atomicAdd(&counts[(b * PH + iy0 + 1) * PW + (ix0 + 1)], 1u);
}

__global__ __launch_bounds__(256) void scan_blocks(const u32* __restrict__ in,
                                                   u32* __restrict__ out,
                                                   u32* __restrict__ bsum)
{
    __shared__ u32 sd[256];
    const int tid = threadIdx.x;
    const int base = blockIdx.x * CHUNK + tid * 4;
    u32 v0 = 0, v1 = 0, v2 = 0, v3 = 0;
    if (base + 3 < NC) {
        const uint4 q = *(const uint4*)(in + base);
        v0 = q.x; v1 = q.y; v2 = q.z; v3 = q.w;
    } else {
        if (base     < NC) v0 = in[base];
        if (base + 1 < NC) v1 = in[base + 1];
        if (base + 2 < NC) v2 = in[base + 2];
    }
    const u32 t = v0 + v1 + v2 + v3;
    sd[tid] = t; __syncthreads();
    for (int o = 1; o < 256; o <<= 1) {
        const u32 a = (tid >= o) ? sd[tid - o] : 0u;
        __syncthreads();
        sd[tid] += a;
        __syncthreads();
    }
    const u32 excl = sd[tid] - t;
    if (base + 3 < NC) {
        uint4 q; q.x = excl; q.y = excl + v0; q.z = excl + v0 + v1; q.w = excl + v0 + v1 + v2;
        *(uint4*)(out + base) = q;
    } else {
        if (base     < NC) out[base]     = excl;
        if (base + 1 < NC) out[base + 1] = excl + v0;
        if (base + 2 < NC) out[base + 2] = excl + v0 + v1;
    }
    if (tid == 255) bsum[blockIdx.x] = sd[255];
}

__global__ __launch_bounds__(1024) void scan_bsum(u32* __restrict__ bsum,
                                                  u32* __restrict__ off)
{
    __shared__ u32 sd[1024];
    const int tid = threadIdx.x;
    const u32 v = (tid < NBLK) ? bsum[tid] : 0u;
    sd[tid] = v; __syncthreads();
    for (int o = 1; o < 1024; o <<= 1) {
        const u32 a = (tid >= o) ? sd[tid - o] : 0u;
        __syncthreads();
        sd[tid] += a;
        __syncthreads();
    }
    if (tid < NBLK) bsum[tid] = sd[tid] - v;
    if (tid == 1023) off[NC] = sd[1023];
}

__global__ __launch_bounds__(256) void scan_add(u32* __restrict__ off,
                                                const u32* __restrict__ bsum)
{
    const u32 add = bsum[blockIdx.x];
    if (add == 0) return;
    const int base = blockIdx.x * CHUNK + threadIdx.x * 4;
    if (base + 3 < NC) {
        uint4 q = *(uint4*)(off + base);
        q.x += add; q.y += add; q.z += add; q.w += add;
        *(uint4*)(off + base) = q;
    } else {
        for (int k = 0; k < 4; ++k)
            if (base + k < NC) off[base + k] += add;
    }
}

__global__ __launch_bounds__(256) void fill_kernel(const float* __restrict__ flow,
                                                   const u32* __restrict__ off,
                                                   u32* __restrict__ cur,
                                                   u32* __restrict__ slot_of_src,
                                                   u32* __restrict__ lpos,
                                                   float* __restrict__ lfx,
                                                   float* __restrict__ lfy)
{
    const int x = threadIdx.x, by = blockIdx.x, b = by >> 8, y = by & 255;
    const float fx = (float)x + flow[(b * 2) * HW + y * W + x];
    const float fy = (float)y + flow[(b * 2 + 1) * HW + y * W + x];
    const int ix0 = (int)floorf(fx), iy0 = (int)floorf(fy);
    const int src = b * HW + y * W + x;
    if (ix0 >= -1 && ix0 < W && iy0 >= -1 && iy0 < H) {
        const int cell = (b * PH + iy0 + 1) * PW + (ix0 + 1);
        const u32 slot = off[cell] + atomicAdd(&cur[cell], 1u);
        slot_of_src[src] = slot;
        lpos[slot] = (u32)(y * W + x);
        lfx[slot]  = fx;
        lfy[slot]  = fy;
    } else {
        slot_of_src[src] = 0xFFFFFFFFu;
    }
}

// ---------------- pack: feat planar -> per-entry contiguous ----------------
// Block: 64 consecutive source pixels x CC channels. Coalesced planar reads
// into LDS, then per-entry contiguous writes to packed[slot*CC + c].

__global__ __launch_bounds__(256) void pack_kernel(const float* __restrict__ feat,
                                                   const u32* __restrict__ slot_of_src,
                                                   float* __restrict__ packed,
                                                   int c0, int CC)
{
    __shared__ float lds[64 * 129];   // [pix][cc], stride 129 (conflict-free)
    const int x0 = blockIdx.x * 64, y = blockIdx.y, b = blockIdx.z;
    const int tid = threadIdx.x;
    const float* fbase = feat + (size_t)(b * C + c0) * HW + y * W + x0;
    const int n = CC * 64;
    for (int idx = tid; idx < n; idx += 256) {
        const int cc = idx >> 6, i = idx & 63;
        lds[i * 129 + cc] = fbase[(size_t)cc * HW + i];
    }
    __syncthreads();
    const int wave = tid >> 6, lane = tid & 63;
    const u32* sp = slot_of_src + (size_t)b * HW + y * W + x0;
    for (int p = wave * 16; p < wave * 16 + 16; ++p) {
        const u32 s = sp[p];
        if (s == 0xFFFFFFFFu) continue;
        float* dst = packed + (size_t)s * CC;
        for (int j = lane; j < CC; j += 64)
            dst[j] = lds[p * 129 + j];
    }
}

// ---------------- gather from packed ----------------

__global__ __launch_bounds__(256) void gather_packed(
    const float* __restrict__ packed, const u32* __restrict__ off,
    const float* __restrict__ lfx, const float* __restrict__ lfy,
    float* __restrict__ out, int c0, int CC)
{
    const int t = threadIdx.x;
    const int tile = blockIdx.x, b = blockIdx.y;
    const int ox = ((tile & 15) << 4) | (t & 15);
    const int oy = ((tile >> 4) << 4) | (t >> 4);
    const int opix = oy * W + ox;
    const u32 rb0 = (u32)((b * PH + oy) * PW + ox);
    const u32 s0 = off[rb0],      e0 = off[rb0 + 2];
    const u32 s1 = off[rb0 + PW], e1 = off[rb0 + PW + 2];
    const float fox = (float)ox, foy = (float)oy;

    float scale = 0.f;
    for (int ch = 0; ch < CC; ch += 16) {
        float acc[16];
        #pragma unroll
        for (int c = 0; c < 16; ++c) acc[c] = 0.f;
        float den = 0.f;
        for (int rr = 0; rr < 2; ++rr) {
            u32 i = rr ? s1 : s0;
            const u32 e = rr ? e1 : e0;
            for (; i < e; ++i) {
                const float w = (1.f - fabsf(lfx[i] - fox)) * (1.f - fabsf(lfy[i] - foy));
                den += w;
                const float4* ep = (const float4*)(packed + (size_t)i * CC + ch);
                const float4 q0 = ep[0], q1 = ep[1], q2 = ep[2], q3 = ep[3];
                acc[ 0] = fmaf(w, q0.x, acc[ 0]); acc[ 1] = fmaf(w, q0.y, acc[ 1]);
                acc[ 2] = fmaf(w, q0.z, acc[ 2]); acc[ 3] = fmaf(w, q0.w, acc[ 3]);
                acc[ 4] = fmaf(w, q1.x, acc[ 4]); acc[ 5] = fmaf(w, q1.y, acc[ 5]);
                acc[ 6] = fmaf(w, q1.z, acc[ 6]); acc[ 7] = fmaf(w, q1.w, acc[ 7]);
                acc[ 8] = fmaf(w, q2.x, acc[ 8]); acc[ 9] = fmaf(w, q2.y, acc[ 9]);
                acc[10] = fmaf(w, q2.z, acc[10]); acc[11] = fmaf(w, q2.w, acc[11]);
                acc[12] = fmaf(w, q3.x, acc[12]); acc[13] = fmaf(w, q3.y, acc[13]);
                acc[14] = fmaf(w, q3.z, acc[14]); acc[15] = fmaf(w, q3.w, acc[15]);
            }
        }
        if (ch == 0) scale = E1 / (E1 * den + EPS);
        float* op = out + (size_t)(b * C + c0 + ch) * HW + opix;
        #pragma unroll
        for (int c = 0; c < 16; ++c) op[(size_t)c * HW] = acc[c] * scale;
    }
    if (c0 == 0)
        out[(size_t)(B * C) * HW + (size_t)b * HW + opix] = 1.0f;  // metric
}

// ---------------- fallback: round-2 planar gather ----------------

__global__ __launch_bounds__(256) void gather_kernel(
    const float* __restrict__ feat, const u32* __restrict__ off,
    const u32* __restrict__ lpos, const float* __restrict__ lfx,
    const float* __restrict__ lfy, float* __restrict__ out)
{
    const int t = threadIdx.x;
    const int tile = blockIdx.x, b = blockIdx.y;
    const int ox = ((tile & 15) << 4) | (t & 15);
    const int oy = ((tile >> 4) << 4) | (t >> 4);
    const int opix = oy * W + ox;
    const u32 rb0 = (u32)((b * PH + oy) * PW + ox);
    const u32 s0 = off[rb0],      e0 = off[rb0 + 2];
    const u32 s1 = off[rb0 + PW], e1 = off[rb0 + PW + 2];
    const float fox = (float)ox, foy = (float)oy;
    float den = 0.f;
    for (int rr = 0; rr < 2; ++rr) {
        u32 i = rr ? s1 : s0;
        const u32 e = rr ? e1 : e0;
        for (; i < e; ++i)
            den += (1.f - fabsf(lfx[i] - fox)) * (1.f - fabsf(lfy[i] - foy));
    }
    const float scale = E1 / (E1 * den + EPS);
    for (int ch = 0; ch < C; ch += 16) {
        float acc[16];
        #pragma unroll
        for (int c = 0; c < 16; ++c) acc[c] = 0.f;
        const float* fb = feat + (size_t)(b * C + ch) * HW;
        for (int rr = 0; rr < 2; ++rr) {
            u32 i = rr ? s1 : s0;
            const u32 e = rr ? e1 : e0;
            for (; i < e; ++i) {
                const float w = (1.f - fabsf(lfx[i] - fox)) * (1.f - fabsf(lfy[i] - foy));
                const float* fp = fb + lpos[i];
                #pragma unroll
                for (int c = 0; c < 16; ++c)
                    acc[c] = fmaf(w, fp[(size_t)c * HW], acc[c]);
            }
        }
        float* op = out + (size_t)(b * C + ch) * HW + opix;
        #pragma unroll
        for (int c = 0; c < 16; ++c) op[(size_t)c * HW] = acc[c] * scale;
    }
    out[(size_t)(B * C) * HW + (size_t)b * HW + opix] = 1.0f;
}

// ---------------- fallback: round-1 atomic path ----------------

static constexpr int CG = 8, CPG = C / CG;

__global__ __launch_bounds__(256) void splat_kernel(
    const float* __restrict__ feat, const float* __restrict__ flow,
    float* __restrict__ num, float* __restrict__ den)
{
    const int x = threadIdx.x, by = blockIdx.x, b = by >> 8, y = by & (H - 1);
    const int cg = blockIdx.y;
    const float fx = (float)x + flow[(b * 2 * H + y) * W + x];
    const float fy = (float)y + flow[((b * 2 + 1) * H + y) * W + x];
    const float x0f = floorf(fx), y0f = floorf(fy);
    const int ix0 = (int)x0f, iy0 = (int)y0f;
    const float ax = fx - x0f, ay = fy - y0f;
    const float w00 = (1.f - ax) * (1.f - ay), w10 = ax * (1.f - ay);
    const float w01 = (1.f - ax) * ay,         w11 = ax * ay;
    const bool vx0 = (unsigned)ix0       < (unsigned)W;
    const bool vx1 = (unsigned)(ix0 + 1) < (unsigned)W;
    const bool vy0 = (unsigned)iy0       < (unsigned)H;
    const bool vy1 = (unsigned)(iy0 + 1) < (unsigned)H;
    const bool v00 = vx0 && vy0, v10 = vx1 && vy0;
    const bool v01 = vx0 && vy1, v11 = vx1 && vy1;
    const int t00 = iy0 * W + ix0, t01 = t00 + W;
    if (cg == 0) {
        float* dn = den + b * HW;
        if (v00) atomicAdd(dn + t00,     w00);
        if (v10) atomicAdd(dn + t00 + 1, w10);
        if (v01) atomicAdd(dn + t01,     w01);
        if (v11) atomicAdd(dn + t01 + 1, w11);
    }
    const int c0 = cg * CPG;
    const float* fp = feat + ((size_t)(b * C + c0)) * HW + y * W + x;
    float*       np = num  + ((size_t)(b * C + c0)) * HW;
    for (int c = 0; c < CPG; ++c) {
        const float v = fp[(size_t)c * HW];
        float* nc = np + (size_t)c * HW;
        if (v00) atomicAdd(nc + t00,     v * w00);
        if (v10) atomicAdd(nc + t00 + 1, v * w10);
        if (v01) atomicAdd(nc + t01,     v * w01);
        if (v11) atomicAdd(nc + t01 + 1, v * w11);
    }
}

__global__ __launch_bounds__(256) void normalize_kernel(float* __restrict__ num,
                                                        float* __restrict__ den)
{
    const int x = threadIdx.x, by = blockIdx.x, b = by >> 8;
    const int pix = by * W + x;
    const float d = den[pix];
    const float s = E1 / (E1 * d + EPS);
    float* p = num + (size_t)b * (C - 1) * HW + pix;
    for (int c = 0; c < C; ++c) p[(size_t)c * HW] *= s;
    den[pix] = 1.0f;
}

// ---------------- launch ----------------

extern "C" void kernel_launch(void* const* d_in, const int* in_sizes, int n_in,
                              void* d_out, int out_size, void* d_ws, size_t ws_size,
                              hipStream_t stream) {
    const float* feat = (const float*)d_in[0];
    const float* flow = (const float*)d_in[1];
    float* out = (float*)d_out;

    const size_t o_counts = 0;
    const size_t o_off    = o_counts + (size_t)NC * 4;
    const size_t o_bsum   = (o_off + (size_t)(NC + 1) * 4 + 15) & ~(size_t)15;
    const size_t o_slot   = (o_bsum + 4096 + 15) & ~(size_t)15;
    const size_t o_lpos   = o_slot + (size_t)S * 4;
    const size_t o_lfx    = o_lpos + (size_t)S * 4;
    const size_t o_lfy    = o_lfx + (size_t)S * 4;
    const size_t meta_end = o_lfy + (size_t)S * 4;               // ~14.4 MB
    const size_t o_packed = (meta_end + 255) & ~(size_t)255;

    int CC = 0;
    for (int cand = 128; cand >= 16; cand >>= 1)
        if (o_packed + (size_t)S * cand * 4 <= ws_size) { CC = cand; break; }

    if (meta_end <= ws_size) {
        u32*   counts = (u32*)  ((char*)d_ws + o_counts);
        u32*   off    = (u32*)  ((char*)d_ws + o_off);
        u32*   bsum   = (u32*)  ((char*)d_ws + o_bsum);
        u32*   slot   = (u32*)  ((char*)d_ws + o_slot);
        u32*   lpos   = (u32*)  ((char*)d_ws + o_lpos);
        float* lfx    = (float*)((char*)d_ws + o_lfx);
        float* lfy    = (float*)((char*)d_ws + o_lfy);
        float* packed = (float*)((char*)d_ws + o_packed);

        hipMemsetAsync(counts, 0, (size_t)NC * 4, stream);
        count_kernel<<<B * H, 256, 0, stream>>>(flow, counts);
        scan_blocks<<<NBLK, 256, 0, stream>>>(counts, off, bsum);
        scan_bsum<<<1, 1024, 0, stream>>>(bsum, off);
        scan_add<<<NBLK, 256, 0, stream>>>(off, bsum);
        hipMemsetAsync(counts, 0, (size_t)NC * 4, stream);  // reuse as cursor
        fill_kernel<<<B * H, 256, 0, stream>>>(flow, off, counts, slot, lpos, lfx, lfy);

        if (CC) {
            for (int c0 = 0; c0 < C; c0 += CC) {
                pack_kernel<<<dim3(W / 64, H, B), 256, 0, stream>>>(feat, slot, packed, c0, CC);
                gather_packed<<<dim3(256, B), 256, 0, stream>>>(packed, off, lfx, lfy, out, c0, CC);
            }
        } else {
            gather_kernel<<<dim3(256, B), 256, 0, stream>>>(feat, off, lpos, lfx, lfy, out);
        }
    } else {
        float* num = out;
        float* den = out + (size_t)B * C * HW;
        hipMemsetAsync(d_out, 0, (size_t)out_size * sizeof(float), stream);
        splat_kernel<<<dim3(B * H, CG), 256, 0, stream>>>(feat, flow, num, den);
        normalize_kernel<<<B * H, 256, 0, stream>>>(num, den);
    }
}